// Round 1
// baseline (437.543 us; speedup 1.0000x reference)
//
#include <hip/hip_runtime.h>

// ---------------------------------------------------------------------------
// SelfAttention: x -> QKV proj -> RMSNorm -> RoPE -> softmax attn -> out proj
// B=2 S=2048 DIM=2048 NH=16 HD=128  (all shapes hard-coded)
// ---------------------------------------------------------------------------

typedef __attribute__((ext_vector_type(8))) short bf16x8;
typedef __attribute__((ext_vector_type(4))) float f32x4;

__device__ __forceinline__ unsigned short f2bf(float f) {
  unsigned int u = __builtin_bit_cast(unsigned int, f);
  u = (u + 0x7FFFu + ((u >> 16) & 1u)) >> 16;  // RNE
  return (unsigned short)u;
}
__device__ __forceinline__ float bf2f(unsigned short h) {
  unsigned int u = ((unsigned int)h) << 16;
  return __builtin_bit_cast(float, u);
}

#define GLOAD16(gp, lp)                                                        \
  __builtin_amdgcn_global_load_lds(                                            \
      (__attribute__((address_space(1))) void*)(gp),                           \
      (__attribute__((address_space(3))) void*)(lp), 16, 0, 0)

// ---------------- f32 -> bf16 convert (x) ----------------
__global__ __launch_bounds__(256) void k_convert(const float* __restrict__ in,
                                                 unsigned short* __restrict__ out,
                                                 int n8) {
  int i = blockIdx.x * 256 + threadIdx.x;
  const int stride = gridDim.x * 256;
  for (; i < n8; i += stride) {
    const float4* p = (const float4*)in + (size_t)i * 2;
    float4 a = p[0], b = p[1];
    bf16x8 v;
    v[0] = (short)f2bf(a.x); v[1] = (short)f2bf(a.y);
    v[2] = (short)f2bf(a.z); v[3] = (short)f2bf(a.w);
    v[4] = (short)f2bf(b.x); v[5] = (short)f2bf(b.y);
    v[6] = (short)f2bf(b.z); v[7] = (short)f2bf(b.w);
    *(bf16x8*)(out + (size_t)i * 8) = v;
  }
}

// ---------------- transpose + convert: out[c][r] = bf16(in[r][c]) ----------
__global__ __launch_bounds__(256) void k_transpose(const float* __restrict__ in,
                                                   unsigned short* __restrict__ out,
                                                   int R, int C) {
  __shared__ float tile[32][33];
  const int c0 = blockIdx.x * 32, r0 = blockIdx.y * 32;
  const int tx = threadIdx.x, ty = threadIdx.y;
#pragma unroll
  for (int i = 0; i < 4; i++)
    tile[ty + i * 8][tx] = in[(size_t)(r0 + ty + i * 8) * C + c0 + tx];
  __syncthreads();
#pragma unroll
  for (int i = 0; i < 4; i++)
    out[(size_t)(c0 + ty + i * 8) * R + r0 + tx] = f2bf(tile[tx][ty + i * 8]);
}

// ---------------- GEMM: C[m][n] = sum_k A[m][k] * BT[n][k] (+bias) ---------
// m97-style: 128x128 tile, BK=32, 4 waves (2x2 of 64x64), global_load_lds x16
// OUTF32: 0 -> bf16 out, 1 -> f32 out.  BIASMODE: 0 none, 1 row, 2 col.
template <int OUTF32, int BIASMODE>
__global__ __launch_bounds__(256) void k_gemm(const unsigned short* __restrict__ A,
                                              const unsigned short* __restrict__ BT,
                                              void* __restrict__ Cout,
                                              const float* __restrict__ bias,
                                              int M, int N, int K) {
  __shared__ unsigned short As[128 * 32];
  __shared__ unsigned short Bs[128 * 32];
  const int tid = threadIdx.x;
  const int lane = tid & 63, w = tid >> 6;
  const int g = lane >> 4, cc = lane & 15;
  const int n0 = blockIdx.x * 128, m0 = blockIdx.y * 128;
  const int wm = (w >> 1) * 64, wn = (w & 1) * 64;
  f32x4 acc[4][4] = {};
  const unsigned short* Ab = A + (size_t)m0 * K;
  const unsigned short* Bb = BT + (size_t)n0 * K;
  const int r0 = tid >> 2, c0 = (tid & 3) * 8;
  for (int kt = 0; kt < K; kt += 32) {
    GLOAD16(Ab + (size_t)r0 * K + kt + c0, As + tid * 8);
    GLOAD16(Ab + (size_t)(r0 + 64) * K + kt + c0, As + (tid + 256) * 8);
    GLOAD16(Bb + (size_t)r0 * K + kt + c0, Bs + tid * 8);
    GLOAD16(Bb + (size_t)(r0 + 64) * K + kt + c0, Bs + (tid + 256) * 8);
    __syncthreads();
    bf16x8 af[4], bfr[4];
#pragma unroll
    for (int m4 = 0; m4 < 4; m4++)
      af[m4] = *(const bf16x8*)(As + (wm + m4 * 16 + cc) * 32 + g * 8);
#pragma unroll
    for (int n4 = 0; n4 < 4; n4++)
      bfr[n4] = *(const bf16x8*)(Bs + (wn + n4 * 16 + cc) * 32 + g * 8);
#pragma unroll
    for (int m4 = 0; m4 < 4; m4++)
#pragma unroll
      for (int n4 = 0; n4 < 4; n4++)
        acc[m4][n4] = __builtin_amdgcn_mfma_f32_16x16x32_bf16(af[m4], bfr[n4],
                                                              acc[m4][n4], 0, 0, 0);
    __syncthreads();
  }
#pragma unroll
  for (int m4 = 0; m4 < 4; m4++)
#pragma unroll
    for (int n4 = 0; n4 < 4; n4++) {
      const int col = n0 + wn + n4 * 16 + cc;
#pragma unroll
      for (int r = 0; r < 4; r++) {
        const int row = m0 + wm + m4 * 16 + g * 4 + r;
        float v = acc[m4][n4][r];
        if (BIASMODE == 1) v += bias[row];
        if (BIASMODE == 2) v += bias[col];
        if (OUTF32)
          ((float*)Cout)[(size_t)row * N + col] = v;
        else
          ((unsigned short*)Cout)[(size_t)row * N + col] = f2bf(v);
      }
    }
}

// ---------------- QK epilogue: bias + RMSNorm + RoPE -> Q,K [b,h,s,d] ------
__global__ __launch_bounds__(256) void k_qk_epi(const unsigned short* __restrict__ Yqk, // [4096][4096]
                                                const float* __restrict__ q_b,
                                                const float* __restrict__ k_b,
                                                const float* __restrict__ nqw,
                                                const float* __restrict__ nkw,
                                                const float* __restrict__ freqs, // [1024][64][2]
                                                const int* __restrict__ inner_t, // [2][2]
                                                unsigned short* __restrict__ Q,
                                                unsigned short* __restrict__ K) {
  const int row = blockIdx.x;          // b*2048 + s
  const int b = row >> 11, s = row & 2047;
  const int t = threadIdx.x;
  const unsigned short* yr = Yqk + (size_t)row * 4096;
  bf16x8 yq = *(const bf16x8*)(yr + t * 8);
  bf16x8 yk = *(const bf16x8*)(yr + 2048 + t * 8);
  float4 qb0 = *(const float4*)(q_b + t * 8), qb1 = *(const float4*)(q_b + t * 8 + 4);
  float4 kb0 = *(const float4*)(k_b + t * 8), kb1 = *(const float4*)(k_b + t * 8 + 4);
  float q[8], k[8];
  const float* qbp = &qb0.x;  // contiguous 8 floats? not guaranteed; unroll manually
  (void)qbp;
  q[0] = bf2f((unsigned short)yq[0]) + qb0.x; q[1] = bf2f((unsigned short)yq[1]) + qb0.y;
  q[2] = bf2f((unsigned short)yq[2]) + qb0.z; q[3] = bf2f((unsigned short)yq[3]) + qb0.w;
  q[4] = bf2f((unsigned short)yq[4]) + qb1.x; q[5] = bf2f((unsigned short)yq[5]) + qb1.y;
  q[6] = bf2f((unsigned short)yq[6]) + qb1.z; q[7] = bf2f((unsigned short)yq[7]) + qb1.w;
  k[0] = bf2f((unsigned short)yk[0]) + kb0.x; k[1] = bf2f((unsigned short)yk[1]) + kb0.y;
  k[2] = bf2f((unsigned short)yk[2]) + kb0.z; k[3] = bf2f((unsigned short)yk[3]) + kb0.w;
  k[4] = bf2f((unsigned short)yk[4]) + kb1.x; k[5] = bf2f((unsigned short)yk[5]) + kb1.y;
  k[6] = bf2f((unsigned short)yk[6]) + kb1.z; k[7] = bf2f((unsigned short)yk[7]) + kb1.w;
  float ssq = 0.f, ssk = 0.f;
#pragma unroll
  for (int j = 0; j < 8; j++) { ssq += q[j] * q[j]; ssk += k[j] * k[j]; }
#pragma unroll
  for (int off = 32; off; off >>= 1) {
    ssq += __shfl_xor(ssq, off);
    ssk += __shfl_xor(ssk, off);
  }
  __shared__ float red[8];
  const int w = t >> 6;
  if ((t & 63) == 0) { red[w] = ssq; red[4 + w] = ssk; }
  __syncthreads();
  const float sq = red[0] + red[1] + red[2] + red[3];
  const float sk = red[4] + red[5] + red[6] + red[7];
  const float rq = __builtin_amdgcn_rsqf(sq * (1.0f / 2048.0f) + 1e-6f);
  const float rk = __builtin_amdgcn_rsqf(sk * (1.0f / 2048.0f) + 1e-6f);
  float4 nq0 = *(const float4*)(nqw + t * 8), nq1 = *(const float4*)(nqw + t * 8 + 4);
  float4 nk0 = *(const float4*)(nkw + t * 8), nk1 = *(const float4*)(nkw + t * 8 + 4);
  q[0] *= rq * nq0.x; q[1] *= rq * nq0.y; q[2] *= rq * nq0.z; q[3] *= rq * nq0.w;
  q[4] *= rq * nq1.x; q[5] *= rq * nq1.y; q[6] *= rq * nq1.z; q[7] *= rq * nq1.w;
  k[0] *= rk * nk0.x; k[1] *= rk * nk0.y; k[2] *= rk * nk0.z; k[3] *= rk * nk0.w;
  k[4] *= rk * nk1.x; k[5] *= rk * nk1.y; k[6] *= rk * nk1.z; k[7] *= rk * nk1.w;
  // RoPE: s -> (f,h,w) with HW grid 8x16x16, pairs are adjacent elems
  const int f = s >> 8, hh = (s >> 4) & 15, ww = s & 15;
  const int it0 = inner_t[b * 2], it1 = inner_t[b * 2 + 1];
  const int trow = ((f >= it0) + (f >= it0 + it1)) * 4 + f;  // SHIFT=4
#pragma unroll
  for (int jj = 0; jj < 4; jj++) {
    const int c = (t * 4 + jj) & 63;              // pair idx within head (C=64)
    const int fr = (c < 22) ? trow : ((c < 43) ? hh : ww);  // CT=22, CT+CH=43
    const float cr = freqs[((size_t)fr * 64 + c) * 2];
    const float ci = freqs[((size_t)fr * 64 + c) * 2 + 1];
    float a = q[2 * jj], bb = q[2 * jj + 1];
    q[2 * jj] = a * cr - bb * ci; q[2 * jj + 1] = a * ci + bb * cr;
    a = k[2 * jj]; bb = k[2 * jj + 1];
    k[2 * jj] = a * cr - bb * ci; k[2 * jj + 1] = a * ci + bb * cr;
  }
  // fold attn scale and log2(e) into Q (softmax done in exp2 domain)
  const float QSCALE = 0.08838834764831845f * 1.4426950408889634f;
  bf16x8 oq, ok;
#pragma unroll
  for (int j = 0; j < 8; j++) {
    oq[j] = (short)f2bf(q[j] * QSCALE);
    ok[j] = (short)f2bf(k[j]);
  }
  const int head = t >> 4, d0 = (t & 15) * 8;
  const size_t off = ((size_t)(b * 16 + head) * 2048 + s) * 128 + d0;
  *(bf16x8*)(Q + off) = oq;
  *(bf16x8*)(K + off) = ok;
}

// ---------------- flash attention -----------------------------------------
// block: 4 waves x 16 q-rows (64-row q-tile); KV-tile = 64 keys.
// K [bh][s][128] bf16; Vt [h*128+d][b*2048+s] bf16 (row stride 4096).
// K/V staged with XOR-swizzled global source + linear LDS dest (rule 21).
__global__ __launch_bounds__(256) void k_attn(const unsigned short* __restrict__ Q,
                                              const unsigned short* __restrict__ K,
                                              const unsigned short* __restrict__ V,
                                              unsigned short* __restrict__ O) {
  __shared__ unsigned short Ks[64 * 128];   // [key][d], byte ^= (key&7)<<4
  __shared__ unsigned short Vs[128 * 64];   // [d][key], byte ^= (d&7)<<4
  __shared__ unsigned short Ps[4 * 16 * 72];  // per-wave P tile, padded rows
  const int tid = threadIdx.x;
  const int lane = tid & 63, w = tid >> 6;
  const int g = lane >> 4, cc = lane & 15;
  const int q0 = blockIdx.x * 64;
  const int bh = blockIdx.y;
  const int b = bh >> 4, h = bh & 15;

  const unsigned short* Qb = Q + ((size_t)bh * 2048 + q0 + w * 16 + cc) * 128;
  bf16x8 qf[4];
#pragma unroll
  for (int kk = 0; kk < 4; kk++) qf[kk] = *(const bf16x8*)(Qb + kk * 32 + g * 8);

  const char* kbase = (const char*)(K + (size_t)bh * 2048 * 128);
  const char* vbase = (const char*)V + ((size_t)h * 128 * 4096 + (size_t)b * 2048) * 2;

  f32x4 acc[8] = {};
  float m[4], l[4];
#pragma unroll
  for (int r = 0; r < 4; r++) { m[r] = -3.0e38f; l[r] = 0.f; }
  unsigned short* Pw = Ps + w * (16 * 72);
  const f32x4 vzero = {0.f, 0.f, 0.f, 0.f};

  for (int s0 = 0; s0 < 2048; s0 += 64) {
    const char* kt0 = kbase + (size_t)s0 * 256;
    const char* vt0 = vbase + (size_t)s0 * 2;
#pragma unroll
    for (int i = 0; i < 4; i++) {
      const int li = i * 256 + tid;
      const int kr = li >> 4;
      const int kc = ((li & 15) * 16) ^ ((kr & 7) << 4);
      GLOAD16(kt0 + kr * 256 + kc, (char*)Ks + li * 16);
      const int vd = li >> 3;
      const int vc = ((li & 7) * 16) ^ ((vd & 7) << 4);
      GLOAD16(vt0 + (size_t)vd * 8192 + vc, (char*)Vs + li * 16);
    }
    __syncthreads();

    // S = Q K^T (already in log2 units via Q pre-scale)
    f32x4 sf[4];
#pragma unroll
    for (int n4 = 0; n4 < 4; n4++) {
      sf[n4] = vzero;
      const int key = n4 * 16 + cc;
      const char* krow = (const char*)Ks + key * 256;
      const int sw = (key & 7) << 4;
#pragma unroll
      for (int kk = 0; kk < 4; kk++) {
        bf16x8 kf = *(const bf16x8*)(krow + ((kk * 64 + g * 16) ^ sw));
        sf[n4] = __builtin_amdgcn_mfma_f32_16x16x32_bf16(qf[kk], kf, sf[n4], 0, 0, 0);
      }
    }
    // online softmax; row r of D-layout = q-row g*4+r, 16 cols spread in group
    float tm[4], sc[4], rs[4];
#pragma unroll
    for (int r = 0; r < 4; r++)
      tm[r] = fmaxf(fmaxf(sf[0][r], sf[1][r]), fmaxf(sf[2][r], sf[3][r]));
#pragma unroll
    for (int off = 1; off <= 8; off <<= 1)
#pragma unroll
      for (int r = 0; r < 4; r++) tm[r] = fmaxf(tm[r], __shfl_xor(tm[r], off));
#pragma unroll
    for (int r = 0; r < 4; r++) {
      const float mn = fmaxf(m[r], tm[r]);
      sc[r] = __builtin_amdgcn_exp2f(m[r] - mn);
      m[r] = mn; rs[r] = 0.f;
    }
#pragma unroll
    for (int n4 = 0; n4 < 4; n4++)
#pragma unroll
      for (int r = 0; r < 4; r++) {
        const float p = __builtin_amdgcn_exp2f(sf[n4][r] - m[r]);
        sf[n4][r] = p; rs[r] += p;
      }
#pragma unroll
    for (int off = 1; off <= 8; off <<= 1)
#pragma unroll
      for (int r = 0; r < 4; r++) rs[r] += __shfl_xor(rs[r], off);
    const f32x4 scv = {sc[0], sc[1], sc[2], sc[3]};
#pragma unroll
    for (int r = 0; r < 4; r++) l[r] = l[r] * sc[r] + rs[r];
#pragma unroll
    for (int d4 = 0; d4 < 8; d4++) acc[d4] *= scv;
    // P (D-layout) -> LDS so it can be re-read in A-layout
#pragma unroll
    for (int n4 = 0; n4 < 4; n4++)
#pragma unroll
      for (int r = 0; r < 4; r++)
        Pw[(g * 4 + r) * 72 + n4 * 16 + cc] = f2bf(sf[n4][r]);
    __syncthreads();
    // O += P V
#pragma unroll
    for (int ks = 0; ks < 2; ks++) {
      bf16x8 pf = *(const bf16x8*)(Pw + cc * 72 + ks * 32 + g * 8);
#pragma unroll
      for (int d4 = 0; d4 < 8; d4++) {
        const int dd = d4 * 16 + cc;
        bf16x8 vf = *(const bf16x8*)((const char*)Vs + dd * 128 +
                                     ((ks * 64 + g * 16) ^ ((dd & 7) << 4)));
        acc[d4] = __builtin_amdgcn_mfma_f32_16x16x32_bf16(pf, vf, acc[d4], 0, 0, 0);
      }
    }
    __syncthreads();
  }
  float inv[4];
#pragma unroll
  for (int r = 0; r < 4; r++) inv[r] = __builtin_amdgcn_rcpf(l[r]);
  unsigned short* Ob = O + (size_t)(b * 2048 + q0 + w * 16) * 2048 + h * 128;
#pragma unroll
  for (int d4 = 0; d4 < 8; d4++)
#pragma unroll
    for (int r = 0; r < 4; r++)
      Ob[(size_t)(g * 4 + r) * 2048 + d4 * 16 + cc] = f2bf(acc[d4][r] * inv[r]);
}

// ---------------------------------------------------------------------------
extern "C" void kernel_launch(void* const* d_in, const int* in_sizes, int n_in,
                              void* d_out, int out_size, void* d_ws, size_t ws_size,
                              hipStream_t stream) {
  const float* x     = (const float*)d_in[0];
  const float* q_w   = (const float*)d_in[1];
  const float* q_b   = (const float*)d_in[2];
  const float* k_w   = (const float*)d_in[3];
  const float* k_b   = (const float*)d_in[4];
  const float* v_w   = (const float*)d_in[5];
  const float* v_b   = (const float*)d_in[6];
  const float* o_w   = (const float*)d_in[7];
  const float* o_b   = (const float*)d_in[8];
  const float* nqw   = (const float*)d_in[9];
  const float* nkw   = (const float*)d_in[10];
  const float* freqs = (const float*)d_in[11];
  const int* inner_t = (const int*)d_in[14];

  const size_t NEED = (size_t)112 << 20;
  if (ws_size < NEED) return;  // workspace too small -> fail validation loudly

  char* ws = (char*)d_ws;
  unsigned short* xb   = (unsigned short*)(ws);                    // 16MB (later Q)
  unsigned short* WqkT = (unsigned short*)(ws + ((size_t)16 << 20)); // 16MB (later O)
  unsigned short* WvT  = (unsigned short*)(ws + ((size_t)32 << 20)); // 8MB
  unsigned short* WoT  = (unsigned short*)(ws + ((size_t)40 << 20)); // 8MB
  unsigned short* Yqk  = (unsigned short*)(ws + ((size_t)48 << 20)); // 32MB
  unsigned short* Vt   = (unsigned short*)(ws + ((size_t)80 << 20)); // 16MB
  unsigned short* Kr   = (unsigned short*)(ws + ((size_t)96 << 20)); // 16MB
  unsigned short* Qr   = xb;     // reuse: xb dead after GEMM-V
  unsigned short* Orow = WqkT;   // reuse: WqkT dead after GEMM1

  dim3 tb(32, 8);
  k_convert<<<2048, 256, 0, stream>>>(x, xb, 4096 * 2048 / 8);
  k_transpose<<<dim3(64, 64), tb, 0, stream>>>(q_w, WqkT, 2048, 2048);
  k_transpose<<<dim3(64, 64), tb, 0, stream>>>(k_w, WqkT + (size_t)2048 * 2048, 2048, 2048);
  k_transpose<<<dim3(64, 64), tb, 0, stream>>>(v_w, WvT, 2048, 2048);
  k_transpose<<<dim3(64, 64), tb, 0, stream>>>(o_w, WoT, 2048, 2048);
  // Yqk[b*S+s][0:2048]=x@q_w, [2048:4096]=x@k_w  (bias added in epilogue)
  k_gemm<0, 0><<<dim3(32, 32), 256, 0, stream>>>(xb, WqkT, Yqk, nullptr, 4096, 4096, 2048);
  // Vt[h*128+d][b*S+s] = (x@v_w)^T + v_b[row]
  k_gemm<0, 1><<<dim3(32, 16), 256, 0, stream>>>(WvT, xb, Vt, v_b, 2048, 4096, 2048);
  k_qk_epi<<<4096, 256, 0, stream>>>(Yqk, q_b, k_b, nqw, nkw, freqs, inner_t, Qr, Kr);
  k_attn<<<dim3(32, 32), 256, 0, stream>>>(Qr, Kr, Vt, Orow);
  // out = O @ o_w + o_b  (f32)
  k_gemm<1, 2><<<dim3(16, 32), 256, 0, stream>>>(Orow, WoT, (float*)d_out, o_b, 4096, 2048, 2048);
}

// Round 2
// 369.907 us; speedup vs baseline: 1.1828x; 1.1828x over previous
//
#include <hip/hip_runtime.h>

// ---------------------------------------------------------------------------
// SelfAttention: x -> QKV proj -> RMSNorm -> RoPE -> softmax attn -> out proj
// B=2 S=2048 DIM=2048 NH=16 HD=128  (all shapes hard-coded)
// ---------------------------------------------------------------------------

typedef __attribute__((ext_vector_type(8))) short bf16x8;
typedef __attribute__((ext_vector_type(4))) float f32x4;

__device__ __forceinline__ unsigned short f2bf(float f) {
  unsigned int u = __builtin_bit_cast(unsigned int, f);
  u = (u + 0x7FFFu + ((u >> 16) & 1u)) >> 16;  // RNE
  return (unsigned short)u;
}
__device__ __forceinline__ float bf2f(unsigned short h) {
  unsigned int u = ((unsigned int)h) << 16;
  return __builtin_bit_cast(float, u);
}

#define GLOAD16(gp, lp)                                                        \
  __builtin_amdgcn_global_load_lds(                                            \
      (__attribute__((address_space(1))) void*)(gp),                           \
      (__attribute__((address_space(3))) void*)(lp), 16, 0, 0)

// ---------------- f32 -> bf16 convert (x) ----------------
__global__ __launch_bounds__(256) void k_convert(const float* __restrict__ in,
                                                 unsigned short* __restrict__ out,
                                                 int n8) {
  int i = blockIdx.x * 256 + threadIdx.x;
  const int stride = gridDim.x * 256;
  for (; i < n8; i += stride) {
    const float4* p = (const float4*)in + (size_t)i * 2;
    float4 a = p[0], b = p[1];
    bf16x8 v;
    v[0] = (short)f2bf(a.x); v[1] = (short)f2bf(a.y);
    v[2] = (short)f2bf(a.z); v[3] = (short)f2bf(a.w);
    v[4] = (short)f2bf(b.x); v[5] = (short)f2bf(b.y);
    v[6] = (short)f2bf(b.z); v[7] = (short)f2bf(b.w);
    *(bf16x8*)(out + (size_t)i * 8) = v;
  }
}

// ---------------- transpose + convert: out[c][r] = bf16(in[r][c]) ----------
__global__ __launch_bounds__(256) void k_transpose(const float* __restrict__ in,
                                                   unsigned short* __restrict__ out,
                                                   int R, int C) {
  __shared__ float tile[32][33];
  const int c0 = blockIdx.x * 32, r0 = blockIdx.y * 32;
  const int tx = threadIdx.x, ty = threadIdx.y;
#pragma unroll
  for (int i = 0; i < 4; i++)
    tile[ty + i * 8][tx] = in[(size_t)(r0 + ty + i * 8) * C + c0 + tx];
  __syncthreads();
#pragma unroll
  for (int i = 0; i < 4; i++)
    out[(size_t)(c0 + ty + i * 8) * R + r0 + tx] = f2bf(tile[tx][ty + i * 8]);
}

// ---------------- GEMM: C[m][n] = sum_k A[m][k] * BT[n][k] (+bias) ---------
// m97-style: 128x128 tile, BK=32, 4 waves (2x2 of 64x64), global_load_lds x16
// OUTF32: 0 -> bf16 out, 1 -> f32 out.  BIASMODE: 0 none, 1 row, 2 col.
template <int OUTF32, int BIASMODE>
__global__ __launch_bounds__(256) void k_gemm(const unsigned short* __restrict__ A,
                                              const unsigned short* __restrict__ BT,
                                              void* __restrict__ Cout,
                                              const float* __restrict__ bias,
                                              int M, int N, int K) {
  __shared__ unsigned short As[128 * 32];
  __shared__ unsigned short Bs[128 * 32];
  const int tid = threadIdx.x;
  const int lane = tid & 63, w = tid >> 6;
  const int g = lane >> 4, cc = lane & 15;
  const int n0 = blockIdx.x * 128, m0 = blockIdx.y * 128;
  const int wm = (w >> 1) * 64, wn = (w & 1) * 64;
  f32x4 acc[4][4] = {};
  const unsigned short* Ab = A + (size_t)m0 * K;
  const unsigned short* Bb = BT + (size_t)n0 * K;
  const int r0 = tid >> 2, c0 = (tid & 3) * 8;
  for (int kt = 0; kt < K; kt += 32) {
    GLOAD16(Ab + (size_t)r0 * K + kt + c0, As + tid * 8);
    GLOAD16(Ab + (size_t)(r0 + 64) * K + kt + c0, As + (tid + 256) * 8);
    GLOAD16(Bb + (size_t)r0 * K + kt + c0, Bs + tid * 8);
    GLOAD16(Bb + (size_t)(r0 + 64) * K + kt + c0, Bs + (tid + 256) * 8);
    __syncthreads();
    bf16x8 af[4], bfr[4];
#pragma unroll
    for (int m4 = 0; m4 < 4; m4++)
      af[m4] = *(const bf16x8*)(As + (wm + m4 * 16 + cc) * 32 + g * 8);
#pragma unroll
    for (int n4 = 0; n4 < 4; n4++)
      bfr[n4] = *(const bf16x8*)(Bs + (wn + n4 * 16 + cc) * 32 + g * 8);
#pragma unroll
    for (int m4 = 0; m4 < 4; m4++)
#pragma unroll
      for (int n4 = 0; n4 < 4; n4++)
        acc[m4][n4] = __builtin_amdgcn_mfma_f32_16x16x32_bf16(af[m4], bfr[n4],
                                                              acc[m4][n4], 0, 0, 0);
    __syncthreads();
  }
#pragma unroll
  for (int m4 = 0; m4 < 4; m4++)
#pragma unroll
    for (int n4 = 0; n4 < 4; n4++) {
      const int col = n0 + wn + n4 * 16 + cc;
#pragma unroll
      for (int r = 0; r < 4; r++) {
        const int row = m0 + wm + m4 * 16 + g * 4 + r;
        float v = acc[m4][n4][r];
        if (BIASMODE == 1) v += bias[row];
        if (BIASMODE == 2) v += bias[col];
        if (OUTF32)
          ((float*)Cout)[(size_t)row * N + col] = v;
        else
          ((unsigned short*)Cout)[(size_t)row * N + col] = f2bf(v);
      }
    }
}

// ---------------- QK epilogue: bias + RMSNorm + RoPE -> Q,K [b,h,s,d] ------
__global__ __launch_bounds__(256) void k_qk_epi(const unsigned short* __restrict__ Yqk, // [4096][4096]
                                                const float* __restrict__ q_b,
                                                const float* __restrict__ k_b,
                                                const float* __restrict__ nqw,
                                                const float* __restrict__ nkw,
                                                const float* __restrict__ freqs, // [1024][64][2]
                                                const int* __restrict__ inner_t, // [2][2]
                                                unsigned short* __restrict__ Q,
                                                unsigned short* __restrict__ K) {
  const int row = blockIdx.x;          // b*2048 + s
  const int b = row >> 11, s = row & 2047;
  const int t = threadIdx.x;
  const unsigned short* yr = Yqk + (size_t)row * 4096;
  bf16x8 yq = *(const bf16x8*)(yr + t * 8);
  bf16x8 yk = *(const bf16x8*)(yr + 2048 + t * 8);
  float4 qb0 = *(const float4*)(q_b + t * 8), qb1 = *(const float4*)(q_b + t * 8 + 4);
  float4 kb0 = *(const float4*)(k_b + t * 8), kb1 = *(const float4*)(k_b + t * 8 + 4);
  float q[8], k[8];
  q[0] = bf2f((unsigned short)yq[0]) + qb0.x; q[1] = bf2f((unsigned short)yq[1]) + qb0.y;
  q[2] = bf2f((unsigned short)yq[2]) + qb0.z; q[3] = bf2f((unsigned short)yq[3]) + qb0.w;
  q[4] = bf2f((unsigned short)yq[4]) + qb1.x; q[5] = bf2f((unsigned short)yq[5]) + qb1.y;
  q[6] = bf2f((unsigned short)yq[6]) + qb1.z; q[7] = bf2f((unsigned short)yq[7]) + qb1.w;
  k[0] = bf2f((unsigned short)yk[0]) + kb0.x; k[1] = bf2f((unsigned short)yk[1]) + kb0.y;
  k[2] = bf2f((unsigned short)yk[2]) + kb0.z; k[3] = bf2f((unsigned short)yk[3]) + kb0.w;
  k[4] = bf2f((unsigned short)yk[4]) + kb1.x; k[5] = bf2f((unsigned short)yk[5]) + kb1.y;
  k[6] = bf2f((unsigned short)yk[6]) + kb1.z; k[7] = bf2f((unsigned short)yk[7]) + kb1.w;
  float ssq = 0.f, ssk = 0.f;
#pragma unroll
  for (int j = 0; j < 8; j++) { ssq += q[j] * q[j]; ssk += k[j] * k[j]; }
#pragma unroll
  for (int off = 32; off; off >>= 1) {
    ssq += __shfl_xor(ssq, off);
    ssk += __shfl_xor(ssk, off);
  }
  __shared__ float red[8];
  const int w = t >> 6;
  if ((t & 63) == 0) { red[w] = ssq; red[4 + w] = ssk; }
  __syncthreads();
  const float sq = red[0] + red[1] + red[2] + red[3];
  const float sk = red[4] + red[5] + red[6] + red[7];
  const float rq = __builtin_amdgcn_rsqf(sq * (1.0f / 2048.0f) + 1e-6f);
  const float rk = __builtin_amdgcn_rsqf(sk * (1.0f / 2048.0f) + 1e-6f);
  float4 nq0 = *(const float4*)(nqw + t * 8), nq1 = *(const float4*)(nqw + t * 8 + 4);
  float4 nk0 = *(const float4*)(nkw + t * 8), nk1 = *(const float4*)(nkw + t * 8 + 4);
  q[0] *= rq * nq0.x; q[1] *= rq * nq0.y; q[2] *= rq * nq0.z; q[3] *= rq * nq0.w;
  q[4] *= rq * nq1.x; q[5] *= rq * nq1.y; q[6] *= rq * nq1.z; q[7] *= rq * nq1.w;
  k[0] *= rk * nk0.x; k[1] *= rk * nk0.y; k[2] *= rk * nk0.z; k[3] *= rk * nk0.w;
  k[4] *= rk * nk1.x; k[5] *= rk * nk1.y; k[6] *= rk * nk1.z; k[7] *= rk * nk1.w;
  // RoPE: s -> (f,h,w) with HW grid 8x16x16, pairs are adjacent elems
  const int f = s >> 8, hh = (s >> 4) & 15, ww = s & 15;
  const int it0 = inner_t[b * 2], it1 = inner_t[b * 2 + 1];
  const int trow = ((f >= it0) + (f >= it0 + it1)) * 4 + f;  // SHIFT=4
#pragma unroll
  for (int jj = 0; jj < 4; jj++) {
    const int c = (t * 4 + jj) & 63;              // pair idx within head (C=64)
    const int fr = (c < 22) ? trow : ((c < 43) ? hh : ww);  // CT=22, CT+CH=43
    const float cr = freqs[((size_t)fr * 64 + c) * 2];
    const float ci = freqs[((size_t)fr * 64 + c) * 2 + 1];
    float a = q[2 * jj], bb = q[2 * jj + 1];
    q[2 * jj] = a * cr - bb * ci; q[2 * jj + 1] = a * ci + bb * cr;
    a = k[2 * jj]; bb = k[2 * jj + 1];
    k[2 * jj] = a * cr - bb * ci; k[2 * jj + 1] = a * ci + bb * cr;
  }
  // fold attn scale and log2(e) into Q (softmax done in exp2 domain)
  const float QSCALE = 0.08838834764831845f * 1.4426950408889634f;
  bf16x8 oq, ok;
#pragma unroll
  for (int j = 0; j < 8; j++) {
    oq[j] = (short)f2bf(q[j] * QSCALE);
    ok[j] = (short)f2bf(k[j]);
  }
  const int head = t >> 4, d0 = (t & 15) * 8;
  const size_t off = ((size_t)(b * 16 + head) * 2048 + s) * 128 + d0;
  *(bf16x8*)(Q + off) = oq;
  *(bf16x8*)(K + off) = ok;
}

// ---------------- flash attention v2 ---------------------------------------
// 4 waves x 16 q-rows (64-row q-tile); KV-tile = 64 keys, double-buffered.
// Swapped QK^T (S^T = mfma(K,Q)) -> lane-local softmax (q = lane&15).
// Raw s_barrier + counted vmcnt(8): next tile's global_load_lds stays in
// flight across the barrier (T3/T4 minimum 2-phase).
// bh on blockIdx.x -> same-head blocks share an XCD's L2 (T1).
__global__ __launch_bounds__(256) void k_attn(const unsigned short* __restrict__ Q,
                                              const unsigned short* __restrict__ K,
                                              const unsigned short* __restrict__ V,
                                              unsigned short* __restrict__ O) {
  __shared__ unsigned short Ks[2][64 * 128];   // [key][d], byte ^= (key&7)<<4
  __shared__ unsigned short Vs[2][128 * 64];   // [d][key], byte ^= (d&7)<<4
  __shared__ unsigned short Ps[4 * 16 * 72];   // per-wave P tile [q][key], pad 72
  const int tid = threadIdx.x;
  const int lane = tid & 63, w = tid >> 6;
  const int g = lane >> 4, cc = lane & 15;
  const int bh = blockIdx.x;                   // head fastest -> XCD L2 locality
  const int q0 = blockIdx.y * 64;
  const int b = bh >> 4, h = bh & 15;

  const unsigned short* Qb = Q + ((size_t)bh * 2048 + q0 + w * 16 + cc) * 128;
  bf16x8 qf[4];
#pragma unroll
  for (int kk = 0; kk < 4; kk++) qf[kk] = *(const bf16x8*)(Qb + kk * 32 + g * 8);

  const char* kbase = (const char*)(K + (size_t)bh * 2048 * 128);
  const char* vbase = (const char*)V + ((size_t)h * 128 * 4096 + (size_t)b * 2048) * 2;

  f32x4 acc[8] = {};
  float mloc = -3.0e38f, lloc = 0.f;           // per-lane stats for q = w*16+cc
  unsigned short* Pw = Ps + w * (16 * 72);
  const int gbase = (lane & 48) | (((lane >> 4) & 3) << 2);  // lane g*16 + g*4
  const f32x4 vzero = {0.f, 0.f, 0.f, 0.f};

#define ATTN_STAGE(s0, bi)                                                     \
  {                                                                            \
    const char* kt0 = kbase + (size_t)(s0) * 256;                              \
    const char* vt0 = vbase + (size_t)(s0) * 2;                                \
    char* Kd = (char*)(Ks[bi]);                                                \
    char* Vd = (char*)(Vs[bi]);                                                \
    _Pragma("unroll") for (int i = 0; i < 4; i++) {                            \
      const int li = i * 256 + tid;                                            \
      const int kr = li >> 4;                                                  \
      const int kc = ((li & 15) * 16) ^ ((kr & 7) << 4);                       \
      GLOAD16(kt0 + kr * 256 + kc, Kd + li * 16);                              \
      const int vd = li >> 3;                                                  \
      const int vc = ((li & 7) * 16) ^ ((vd & 7) << 4);                        \
      GLOAD16(vt0 + (size_t)vd * 8192 + vc, Vd + li * 16);                     \
    }                                                                          \
  }

  ATTN_STAGE(0, 0);
  for (int t = 0; t < 32; ++t) {
    const int cur = t & 1;
    if (t < 31) {
      ATTN_STAGE((t + 1) * 64, cur ^ 1);
      asm volatile("s_waitcnt vmcnt(8)" ::: "memory");  // tile t landed; t+1 in flight
    } else {
      asm volatile("s_waitcnt vmcnt(0)" ::: "memory");
    }
    __builtin_amdgcn_sched_barrier(0);
    __builtin_amdgcn_s_barrier();

    // S^T = K Q^T : lane (g,cc) holds S[key = n4*16+g*4+r][q = w*16+cc]
    const char* kcur = (const char*)(Ks[cur]);
    const int sw = (cc & 7) << 4;
    f32x4 sf[4];
    __builtin_amdgcn_s_setprio(1);
#pragma unroll
    for (int n4 = 0; n4 < 4; n4++) {
      sf[n4] = vzero;
      const char* krow = kcur + (n4 * 16 + cc) * 256;
#pragma unroll
      for (int kk = 0; kk < 4; kk++) {
        bf16x8 kf = *(const bf16x8*)(krow + ((kk * 64 + g * 16) ^ sw));
        sf[n4] = __builtin_amdgcn_mfma_f32_16x16x32_bf16(kf, qf[kk], sf[n4], 0, 0, 0);
      }
    }
    __builtin_amdgcn_s_setprio(0);

    // lane-local online softmax (16 keys/lane, reduce over 4-lane g-group)
    float tm = fmaxf(fmaxf(sf[0][0], sf[0][1]), fmaxf(sf[0][2], sf[0][3]));
#pragma unroll
    for (int n4 = 1; n4 < 4; n4++)
      tm = fmaxf(tm, fmaxf(fmaxf(sf[n4][0], sf[n4][1]), fmaxf(sf[n4][2], sf[n4][3])));
    tm = fmaxf(tm, __shfl_xor(tm, 16));
    tm = fmaxf(tm, __shfl_xor(tm, 32));
    if (__any(tm > mloc + 8.0f)) {             // defer-max (T13, THR=8 log2 units)
      const float mn = fmaxf(mloc, tm);
      const float sc = __builtin_amdgcn_exp2f(mloc - mn);
      mloc = mn;
      lloc *= sc;
      f32x4 scv;
#pragma unroll
      for (int r = 0; r < 4; r++) scv[r] = __shfl(sc, gbase + r);
#pragma unroll
      for (int d4 = 0; d4 < 8; d4++) acc[d4] *= scv;
    }
    float rs = 0.f;
#pragma unroll
    for (int n4 = 0; n4 < 4; n4++)
#pragma unroll
      for (int r = 0; r < 4; r++) {
        const float p = __builtin_amdgcn_exp2f(sf[n4][r] - mloc);
        rs += p;
        Pw[cc * 72 + n4 * 16 + g * 4 + r] = f2bf(p);
      }
    rs += __shfl_xor(rs, 16);
    rs += __shfl_xor(rs, 32);
    lloc += rs;

    asm volatile("s_waitcnt lgkmcnt(0)" ::: "memory");  // P writes visible in-wave
    __builtin_amdgcn_sched_barrier(0);

    // O += P V   (A = P[q][k] from Pw, B = V^T from Vs)
    const char* vcur = (const char*)(Vs[cur]);
    __builtin_amdgcn_s_setprio(1);
#pragma unroll
    for (int ks = 0; ks < 2; ks++) {
      bf16x8 pf = *(const bf16x8*)(Pw + cc * 72 + ks * 32 + g * 8);
#pragma unroll
      for (int d4 = 0; d4 < 8; d4++) {
        const int dd = d4 * 16 + cc;
        bf16x8 vf = *(const bf16x8*)(vcur + dd * 128 +
                                     ((ks * 64 + g * 16) ^ ((dd & 7) << 4)));
        acc[d4] = __builtin_amdgcn_mfma_f32_16x16x32_bf16(pf, vf, acc[d4], 0, 0, 0);
      }
    }
    __builtin_amdgcn_s_setprio(0);

    asm volatile("s_waitcnt lgkmcnt(0)" ::: "memory");  // reads done before overwrite
    __builtin_amdgcn_sched_barrier(0);
    __builtin_amdgcn_s_barrier();
  }
#undef ATTN_STAGE

  const float invl = __builtin_amdgcn_rcpf(lloc);
  float ir[4];
#pragma unroll
  for (int r = 0; r < 4; r++) ir[r] = __shfl(invl, gbase + r);
  unsigned short* Ob = O + (size_t)(b * 2048 + q0 + w * 16) * 2048 + h * 128;
#pragma unroll
  for (int d4 = 0; d4 < 8; d4++)
#pragma unroll
    for (int r = 0; r < 4; r++)
      Ob[(size_t)(g * 4 + r) * 2048 + d4 * 16 + cc] = f2bf(acc[d4][r] * ir[r]);
}

// ---------------------------------------------------------------------------
extern "C" void kernel_launch(void* const* d_in, const int* in_sizes, int n_in,
                              void* d_out, int out_size, void* d_ws, size_t ws_size,
                              hipStream_t stream) {
  const float* x     = (const float*)d_in[0];
  const float* q_w   = (const float*)d_in[1];
  const float* q_b   = (const float*)d_in[2];
  const float* k_w   = (const float*)d_in[3];
  const float* k_b   = (const float*)d_in[4];
  const float* v_w   = (const float*)d_in[5];
  const float* v_b   = (const float*)d_in[6];
  const float* o_w   = (const float*)d_in[7];
  const float* o_b   = (const float*)d_in[8];
  const float* nqw   = (const float*)d_in[9];
  const float* nkw   = (const float*)d_in[10];
  const float* freqs = (const float*)d_in[11];
  const int* inner_t = (const int*)d_in[14];

  const size_t NEED = (size_t)112 << 20;
  if (ws_size < NEED) return;

  char* ws = (char*)d_ws;
  unsigned short* xb   = (unsigned short*)(ws);                      // 16MB (later Q)
  unsigned short* WqkT = (unsigned short*)(ws + ((size_t)16 << 20)); // 16MB (later O)
  unsigned short* WvT  = (unsigned short*)(ws + ((size_t)32 << 20)); // 8MB
  unsigned short* WoT  = (unsigned short*)(ws + ((size_t)40 << 20)); // 8MB
  unsigned short* Yqk  = (unsigned short*)(ws + ((size_t)48 << 20)); // 32MB
  unsigned short* Vt   = (unsigned short*)(ws + ((size_t)80 << 20)); // 16MB
  unsigned short* Kr   = (unsigned short*)(ws + ((size_t)96 << 20)); // 16MB
  unsigned short* Qr   = xb;     // reuse: xb dead after GEMM-V
  unsigned short* Orow = WqkT;   // reuse: WqkT dead after GEMM1

  dim3 tb(32, 8);
  k_convert<<<2048, 256, 0, stream>>>(x, xb, 4096 * 2048 / 8);
  k_transpose<<<dim3(64, 64), tb, 0, stream>>>(q_w, WqkT, 2048, 2048);
  k_transpose<<<dim3(64, 64), tb, 0, stream>>>(k_w, WqkT + (size_t)2048 * 2048, 2048, 2048);
  k_transpose<<<dim3(64, 64), tb, 0, stream>>>(v_w, WvT, 2048, 2048);
  k_transpose<<<dim3(64, 64), tb, 0, stream>>>(o_w, WoT, 2048, 2048);
  // Yqk[b*S+s][0:2048]=x@q_w, [2048:4096]=x@k_w  (bias added in epilogue)
  k_gemm<0, 0><<<dim3(32, 32), 256, 0, stream>>>(xb, WqkT, Yqk, nullptr, 4096, 4096, 2048);
  // Vt[h*128+d][b*S+s] = (x@v_w)^T + v_b[row]
  k_gemm<0, 1><<<dim3(32, 16), 256, 0, stream>>>(WvT, xb, Vt, v_b, 2048, 4096, 2048);
  k_qk_epi<<<4096, 256, 0, stream>>>(Yqk, q_b, k_b, nqw, nkw, freqs, inner_t, Qr, Kr);
  k_attn<<<dim3(32, 32), 256, 0, stream>>>(Qr, Kr, Vt, Orow);
  // out = O @ o_w + o_b  (f32)
  k_gemm<1, 2><<<dim3(16, 32), 256, 0, stream>>>(Orow, WoT, (float*)d_out, o_b, 4096, 2048, 2048);
}